// Round 7
// baseline (491.645 us; speedup 1.0000x reference)
//
#include <hip/hip_runtime.h>
#include <cstdint>
#include <cstddef>

typedef unsigned short u16;
typedef __bf16 bf16x8 __attribute__((ext_vector_type(8)));
typedef short s16x4 __attribute__((ext_vector_type(4)));
typedef float f32x4 __attribute__((ext_vector_type(4)));

// q is pre-scaled by 1/sqrt(64) * log2(e) so flash softmax runs in exp2 domain
#define SCALE_Q_LOG2E 0.18033688011112042f

static __device__ __forceinline__ float b2f(u16 u){ return __uint_as_float(((unsigned)u)<<16); }
static __device__ __forceinline__ u16 f2b(float f){
  unsigned u = __float_as_uint(f);
  return (u16)((u + 0x7fffu + ((u>>16)&1u)) >> 16);
}
// async global->LDS, 16 B per lane; LDS dest is wave-uniform base + lane*16
static __device__ __forceinline__ void gload_lds16(const void* g, void* l){
  auto gp = reinterpret_cast<__attribute__((address_space(1))) uint32_t*>(reinterpret_cast<uintptr_t>(g));
  auto lp = reinterpret_cast<__attribute__((address_space(3))) uint32_t*>(reinterpret_cast<uintptr_t>(l));
  __builtin_amdgcn_global_load_lds(gp, lp, 16, 0, 0);
}
// 16x16x16 bf16 MFMA (K=16): B-operand k-mapping matches C-layout rows -> P from registers
static __device__ __forceinline__ f32x4 mfma16bf(s16x4 a, s16x4 b, f32x4 c){
#if __has_builtin(__builtin_amdgcn_mfma_f32_16x16x16bf16_1k)
  return __builtin_amdgcn_mfma_f32_16x16x16bf16_1k(a, b, c, 0, 0, 0);
#else
  f32x4 d = c;
  asm volatile("v_mfma_f32_16x16x16_bf16 %0, %1, %2, %0" : "+v"(d) : "v"(a), "v"(b));
  return d;
#endif
}

// ---------------- combined prep: 7 weight transposes + router logits + out-prefill, ONE launch ----------------
__global__ __launch_bounds__(256) void prep_kernel(
    const float* __restrict__ wq, const float* __restrict__ wk,
    const float* __restrict__ wv, const float* __restrict__ wo,
    const float* __restrict__ w1, const float* __restrict__ w3,
    const float* __restrict__ w2, const float* __restrict__ x,
    const float* __restrict__ wr,
    u16* __restrict__ WqkvT, u16* __restrict__ WoT,
    u16* __restrict__ W13T, u16* __restrict__ W2T,
    float* __restrict__ logits, float* __restrict__ out){
  __shared__ float tile[32][33];
  int bx = blockIdx.x;
  if (bx < 12288 || (bx >= 12288 && bx < 13312) || (bx>=13312 && bx<16384)){ }
  if (bx < 16384){
    const float* in; u16* outp; int R, C, rowmap, tcol, trow;
    if (bx < 4096){
      int wsel = bx>>10, tid = bx&1023;
      in = (wsel==0)?wq:(wsel==1)?wk:(wsel==2)?wv:wo;
      outp = (wsel<3) ? (WqkvT + (size_t)wsel*1024*1024) : WoT;
      R=1024; C=1024; rowmap=0; tcol=tid&31; trow=tid>>5;
    } else if (bx < 12288){
      int wsel=(bx-4096)>>12, tid=(bx-4096)&4095;
      in = wsel ? w3 : w1; outp = W13T; R=1024; C=4096; rowmap=1+wsel;
      tcol=tid&127; trow=tid>>7;
    } else {
      int tid = bx-12288;
      in = w2; outp = W2T; R=4096; C=1024; rowmap=0;
      tcol=tid&31; trow=tid>>5;
    }
    int t=threadIdx.x, tx=t&31, ty=t>>5;
    int c0=tcol*32, r0=trow*32;
    #pragma unroll
    for (int i=0;i<4;i++) tile[ty+i*8][tx] = in[(size_t)(r0+ty+i*8)*C + c0+tx];
    __syncthreads();
    #pragma unroll
    for (int i=0;i<4;i++){
      int c = c0+ty+i*8;
      int orow = c;
      if (rowmap==1) orow = (c>>4)*32 + (c&15);
      else if (rowmap==2) orow = (c>>4)*32 + 16 + (c&15);
      outp[(size_t)orow*R + r0+tx] = f2b(tile[tx][ty+i*8]);
    }
  } else if (bx < 18432){
    // router: 4 rows per block, one wave per row
    int row = (bx-16384)*4 + (threadIdx.x>>6);
    int l = threadIdx.x & 63;
    const float4* xr = (const float4*)(x + (size_t)row*1024) + l;
    const float4* wp = (const float4*)wr + l;
    float acc = 0.f;
    #pragma unroll
    for (int c=0;c<4;c++){
      float4 xv = xr[c*64];
      float4 wv = wp[c*64];
      acc += xv.x*wv.x + xv.y*wv.y + xv.z*wv.z + xv.w*wv.w;
    }
    #pragma unroll
    for (int m=1;m<64;m<<=1) acc += __shfl_xor(acc, m, 64);
    if (l==0) logits[row] = acc;
  } else {
    // out prefill: out = x (selected rows overwritten later by gemm_w2 scatter)
    size_t idx = ((size_t)(bx-18432)*256 + threadIdx.x)*4;
    *(float4*)(out+idx) = *(const float4*)(x+idx);
  }
}

// ---------------- bf16 raw transpose (for V), batched over z ----------------
__global__ __launch_bounds__(256) void transpose_bf16(const u16* __restrict__ in, u16* __restrict__ out,
                                                      int R, int C){
  __shared__ u16 tile[32][33];
  size_t zoff = (size_t)blockIdx.z * R * C;
  const u16* ip = in + zoff;
  u16* op = out + zoff;
  int tx = threadIdx.x, ty = threadIdx.y;
  int c0 = blockIdx.x*32, r0 = blockIdx.y*32;
  #pragma unroll
  for (int i=0;i<4;i++) tile[ty+i*8][tx] = ip[(size_t)(r0+ty+i*8)*C + c0+tx];
  __syncthreads();
  #pragma unroll
  for (int i=0;i<4;i++) op[(size_t)(c0+ty+i*8)*R + r0+tx] = tile[tx][ty+i*8];
}

// ---------------- exact top-K (radix select) + softmax weights + inverse map ----------------
static __device__ __forceinline__ unsigned mapkey(float f){
  unsigned u = __float_as_uint(f);
  return (u & 0x80000000u) ? ~u : (u | 0x80000000u);
}
static __device__ unsigned blk_scan_excl(unsigned cnt, unsigned* swav){
  int t = threadIdx.x; int l = t&63, w = t>>6;
  unsigned v = cnt;
  #pragma unroll
  for (int off=1; off<64; off<<=1){
    unsigned n = __shfl_up(v, off, 64);
    if (l >= off) v += n;
  }
  __syncthreads();
  if (l==63) swav[w] = v;
  __syncthreads();
  if (t==0){ unsigned c=0; for (int i=0;i<16;i++){ unsigned tmp=swav[i]; swav[i]=c; c+=tmp; } }
  __syncthreads();
  return swav[w] + v - cnt;
}
__global__ __launch_bounds__(1024) void topk_kernel(const float* __restrict__ logits,
        int* __restrict__ sel, float* __restrict__ rw, int* __restrict__ inv){
  int b = blockIdx.x, t = threadIdx.x;
  int l = t&63, w = t>>6;
  __shared__ float vals[4096];
  __shared__ unsigned hist[256];
  __shared__ unsigned swav[16];
  __shared__ float fwav[16];
  __shared__ unsigned sh_prefix, sh_remaining;
  const float* lgp = logits + b*4096;
  for (int i=t;i<4096;i+=1024) vals[i]=lgp[i];
  if (t==0){ sh_prefix=0u; sh_remaining=2048u; }
  __syncthreads();
  for (int level=0; level<4; level++){
    int shift = 24 - level*8;
    if (t<256) hist[t]=0u;
    __syncthreads();
    unsigned pfx = sh_prefix;
    for (int i=t;i<4096;i+=1024){
      unsigned key = mapkey(vals[i]);
      if (level==0 || (key >> (shift+8)) == pfx)
        atomicAdd(&hist[(key>>shift)&255u], 1u);
    }
    __syncthreads();
    if (t==0){
      unsigned rem = sh_remaining, cum=0u; unsigned bsel=0u;
      for (int bin=255; bin>=0; bin--){
        unsigned hc = hist[bin];
        if (cum + hc >= rem){ bsel=(unsigned)bin; break; }
        cum += hc;
      }
      sh_remaining = rem - cum;
      sh_prefix = (pfx<<8) | bsel;
    }
    __syncthreads();
  }
  unsigned T = sh_prefix;
  unsigned req = sh_remaining;
  int i0 = t*4;
  unsigned gt_[4], eq_[4], fl_[4]; float v_[4];
  #pragma unroll
  for (int j=0;j<4;j++){
    v_[j] = vals[i0+j];
    unsigned key = mapkey(v_[j]);
    gt_[j] = key > T ? 1u:0u;
    eq_[j] = key == T ? 1u:0u;
  }
  unsigned eqbase = blk_scan_excl(eq_[0]+eq_[1]+eq_[2]+eq_[3], swav);
  unsigned er = eqbase;
  #pragma unroll
  for (int j=0;j<4;j++){ fl_[j] = gt_[j] | (eq_[j] & (er < req ? 1u:0u)); er += eq_[j]; }
  unsigned pbase = blk_scan_excl(fl_[0]+fl_[1]+fl_[2]+fl_[3], swav);
  unsigned p = pbase;
  #pragma unroll
  for (int j=0;j<4;j++){
    int i = i0+j;
    if (fl_[j]){ sel[b*2048+(int)p]=i; inv[b*4096+i]=(int)p; p++; }
    else inv[b*4096+i] = -1;
  }
  float mx = fmaxf(fmaxf(v_[0],v_[1]), fmaxf(v_[2],v_[3]));
  #pragma unroll
  for (int m=1;m<64;m<<=1) mx = fmaxf(mx, __shfl_xor(mx,m,64));
  __syncthreads();
  if (l==0) fwav[w]=mx;
  __syncthreads();
  if (t==0){ float g=fwav[0]; for(int i=1;i<16;i++) g=fmaxf(g,fwav[i]); fwav[0]=g; }
  __syncthreads();
  float gm = fwav[0];
  float zz = 0.f;
  #pragma unroll
  for (int j=0;j<4;j++) if (fl_[j]) zz += expf(v_[j]-gm);
  #pragma unroll
  for (int m=1;m<64;m<<=1) zz += __shfl_xor(zz,m,64);
  __syncthreads();
  if (l==0) fwav[w]=zz;
  __syncthreads();
  if (t==0){ float s=0.f; for(int i=0;i<16;i++) s+=fwav[i]; fwav[0]=s; }
  __syncthreads();
  float Z = fwav[0];
  unsigned p2 = pbase;
  #pragma unroll
  for (int j=0;j<4;j++) if (fl_[j]){ rw[b*2048+(int)p2] = expf(v_[j]-gm)/Z; p2++; }
}

// ---------------- (gathered) RMSNorm f32 -> bf16 ----------------
__global__ __launch_bounds__(256) void rmsnorm_kernel(const float* __restrict__ xin,
        const float* __restrict__ gamma, const int* __restrict__ sel,
        u16* __restrict__ xn){
  int r = blockIdx.x;
  int src = r;
  if (sel) src = (r>>11)*4096 + sel[r];
  const float* row = xin + (size_t)src*1024;
  int t = threadIdx.x, l = t&63, w = t>>6;
  int d0 = t*4;
  float4 xv = *(const float4*)(row + d0);
  float ss = xv.x*xv.x + xv.y*xv.y + xv.z*xv.z + xv.w*xv.w;
  #pragma unroll
  for (int m=1;m<64;m<<=1) ss += __shfl_xor(ss,m,64);
  __shared__ float red[4];
  if (l==0) red[w]=ss;
  __syncthreads();
  float tot = red[0]+red[1]+red[2]+red[3];
  float rms = rsqrtf(tot*(1.f/1024.f) + 1e-5f);
  float4 gv = *(const float4*)(gamma + d0);
  u16 o0=f2b(xv.x*rms*gv.x), o1=f2b(xv.y*rms*gv.y), o2=f2b(xv.z*rms*gv.z), o3=f2b(xv.w*rms*gv.w);
  uint2 ov; ov.x = (unsigned)o0 | ((unsigned)o1<<16); ov.y = (unsigned)o2 | ((unsigned)o3<<16);
  *(uint2*)(xn + (size_t)r*1024 + d0) = ov;
}

// XOR-swizzle of 16B k-blocks within an LDS row: conflict-free power-of-2 strides
template<int BK>
static __device__ __forceinline__ int swz(int row, int blk){
  if constexpr (BK==64) return blk ^ (row&7);
  else                  return blk ^ ((row>>1)&3);
}

// ---------------- generic m97-style GEMM: C = A(128xK) * Bt(BNxK)^T (+resid/gather) ----------------
template<int BN, int BK, typename OT>
__global__ __launch_bounds__(256,2) void gemm_bt(const u16* __restrict__ A, const u16* __restrict__ Bt,
        OT* __restrict__ C, const float* __restrict__ resid, const int* __restrict__ sel,
        int M, int N, int Kd){
  __shared__ u16 As[128*BK];
  __shared__ u16 Bs[BN*BK];
  constexpr int NF = BN/32;
  constexpr int KK = BK/32;
  int t = threadIdx.x, w = t>>6, l = t&63, lg = l>>4, ln = l&15;
  int m0 = blockIdx.y*128, n0 = blockIdx.x*BN;
  int wm = (w&1)*64, wn = (w>>1)*(BN/2);
  f32x4 acc[4][NF] = {};
  for (int k0=0; k0<Kd; k0+=BK){
    __syncthreads();
    #pragma unroll
    for (int c=0;c<128*BK*2/4096;c++){
      int off = t*16 + c*4096;
      int row = off/(BK*2), pb = (off%(BK*2))>>4;
      gload_lds16(A + (size_t)(m0+row)*Kd + k0 + swz<BK>(row,pb)*8, &As[c*2048 + w*512]);
    }
    #pragma unroll
    for (int c=0;c<BN*BK*2/4096;c++){
      int off = t*16 + c*4096;
      int row = off/(BK*2), pb = (off%(BK*2))>>4;
      gload_lds16(Bt + (size_t)(n0+row)*Kd + k0 + swz<BK>(row,pb)*8, &Bs[c*2048 + w*512]);
    }
    __syncthreads();
    #pragma unroll
    for (int kk=0;kk<KK;kk++){
      bf16x8 af[4], bfv[NF];
      #pragma unroll
      for (int i=0;i<4;i++){
        int r = wm+i*16+ln;
        af[i] = *(const bf16x8*)&As[r*BK + swz<BK>(r, kk*4+lg)*8];
      }
      #pragma unroll
      for (int i=0;i<NF;i++){
        int r = wn+i*16+ln;
        bfv[i] = *(const bf16x8*)&Bs[r*BK + swz<BK>(r, kk*4+lg)*8];
      }
      #pragma unroll
      for (int mi=0;mi<4;mi++)
        #pragma unroll
        for (int ni=0;ni<NF;ni++)
          acc[mi][ni] = __builtin_amdgcn_mfma_f32_16x16x32_bf16(af[mi], bfv[ni], acc[mi][ni], 0,0,0);
    }
  }
  #pragma unroll
  for (int mi=0;mi<4;mi++){
    #pragma unroll
    for (int ni=0;ni<NF;ni++){
      #pragma unroll
      for (int r=0;r<4;r++){
        int row = m0+wm+mi*16+lg*4+r;
        int col = n0+wn+ni*16+ln;
        float v = acc[mi][ni][r];
        if (resid){
          size_t rrow = sel ? ((size_t)(row>>11)*4096 + sel[row]) : (size_t)row;
          v += resid[rrow*N + col];
        }
        if constexpr (sizeof(OT)==2) C[(size_t)row*N + col] = f2b(v);
        else                          C[(size_t)row*N + col] = v;
      }
    }
  }
}

// ---------------- W2 GEMM with fused MoD scatter epilogue ----------------
// y = g @ W2T; out[b, sel[row], col] = x[b, sel[row], col] + rw[row]*(hbuf[row,col] + y)
__global__ __launch_bounds__(256,2) void gemm_w2(const u16* __restrict__ A, const u16* __restrict__ Bt,
        const float* __restrict__ x, const float* __restrict__ hbuf,
        const int* __restrict__ sel, const float* __restrict__ rw,
        float* __restrict__ out, int Kd){
  constexpr int BN = 64, BK = 64;
  __shared__ u16 As[128*BK];
  __shared__ u16 Bs[BN*BK];
  int t = threadIdx.x, w = t>>6, l = t&63, lg = l>>4, ln = l&15;
  int m0 = blockIdx.y*128, n0 = blockIdx.x*BN;
  int wm = (w&1)*64, wn = (w>>1)*(BN/2);
  f32x4 acc[4][2] = {};
  for (int k0=0; k0<Kd; k0+=BK){
    __syncthreads();
    #pragma unroll
    for (int c=0;c<4;c++){
      int off = t*16 + c*4096;
      int row = off/(BK*2), pb = (off%(BK*2))>>4;
      gload_lds16(A + (size_t)(m0+row)*Kd + k0 + swz<BK>(row,pb)*8, &As[c*2048 + w*512]);
    }
    #pragma unroll
    for (int c=0;c<2;c++){
      int off = t*16 + c*4096;
      int row = off/(BK*2), pb = (off%(BK*2))>>4;
      gload_lds16(Bt + (size_t)(n0+row)*Kd + k0 + swz<BK>(row,pb)*8, &Bs[c*2048 + w*512]);
    }
    __syncthreads();
    #pragma unroll
    for (int kk=0;kk<2;kk++){
      bf16x8 af[4], bfv[2];
      #pragma unroll
      for (int i=0;i<4;i++){
        int r = wm+i*16+ln;
        af[i] = *(const bf16x8*)&As[r*BK + swz<BK>(r, kk*4+lg)*8];
      }
      #pragma unroll
      for (int i=0;i<2;i++){
        int r = wn+i*16+ln;
        bfv[i] = *(const bf16x8*)&Bs[r*BK + swz<BK>(r, kk*4+lg)*8];
      }
      #pragma unroll
      for (int mi=0;mi<4;mi++)
        #pragma unroll
        for (int ni=0;ni<2;ni++)
          acc[mi][ni] = __builtin_amdgcn_mfma_f32_16x16x32_bf16(af[mi], bfv[ni], acc[mi][ni], 0,0,0);
    }
  }
  #pragma unroll
  for (int mi=0;mi<4;mi++){
    int row0 = m0+wm+mi*16+lg*4;
    #pragma unroll
    for (int r=0;r<4;r++){
      int row = row0+r;                 // filtered row 0..4095
      int b = row>>11;
      size_t srow = (size_t)b*4096 + sel[row];
      float wgt = rw[row];
      #pragma unroll
      for (int ni=0;ni<2;ni++){
        int col = n0+wn+ni*16+ln;
        float y = acc[mi][ni][r];
        float v = x[srow*1024 + col] + wgt*(hbuf[(size_t)row*1024 + col] + y);
        out[srow*1024 + col] = v;
      }
    }
  }
}

// ---------------- FFN13 GEMM with fused SwiGLU epilogue (BK=64, swizzled) ----------------
__global__ __launch_bounds__(256,2) void gemm13(const u16* __restrict__ A, const u16* __restrict__ Bt,
        u16* __restrict__ g, int Kd){
  constexpr int BK = 64;
  __shared__ u16 As[128*BK];
  __shared__ u16 Bs[128*BK];
  int t = threadIdx.x, w = t>>6, l = t&63, lg = l>>4, ln = l&15;
  int m0 = blockIdx.y*128, n0 = blockIdx.x*128;
  int wm = (w&1)*64, wn = (w>>1)*64;
  f32x4 acc[4][4] = {};
  for (int k0=0; k0<Kd; k0+=BK){
    __syncthreads();
    #pragma unroll
    for (int c=0;c<4;c++){
      int off = t*16 + c*4096;
      int row = off/(BK*2), pb = (off%(BK*2))>>4;
      gload_lds16(A  + (size_t)(m0+row)*Kd + k0 + swz<BK>(row,pb)*8, &As[c*2048 + w*512]);
      gload_lds16(Bt + (size_t)(n0+row)*Kd + k0 + swz<BK>(row,pb)*8, &Bs[c*2048 + w*512]);
    }
    __syncthreads();
    #pragma unroll
    for (int kk=0;kk<2;kk++){
      bf16x8 af[4], bfv[4];
      #pragma unroll
      for (int i=0;i<4;i++){
        int ra = wm+i*16+ln, rb = wn+i*16+ln;
        af[i]  = *(const bf16x8*)&As[ra*BK + swz<BK>(ra, kk*4+lg)*8];
        bfv[i] = *(const bf16x8*)&Bs[rb*BK + swz<BK>(rb, kk*4+lg)*8];
      }
      #pragma unroll
      for (int mi=0;mi<4;mi++)
        #pragma unroll
        for (int ni=0;ni<4;ni++)
          acc[mi][ni] = __builtin_amdgcn_mfma_f32_16x16x32_bf16(af[mi], bfv[ni], acc[mi][ni], 0,0,0);
    }
  }
  int gbase = (n0+wn)>>1;
  #pragma unroll
  for (int mi=0;mi<4;mi++){
    #pragma unroll
    for (int p=0;p<2;p++){
      #pragma unroll
      for (int r=0;r<4;r++){
        int row = m0+wm+mi*16+lg*4+r;
        int col = gbase + p*16 + ln;
        float a1 = acc[mi][2*p][r], a3 = acc[mi][2*p+1][r];
        float s1 = a1 / (1.f + __expf(-a1));
        g[(size_t)row*4096 + col] = f2b(s1*a3);
      }
    }
  }
}

// ---------------- RoPE + QKV unpack (q scaled by 1/sqrt(HD)*log2e) ----------------
__global__ __launch_bounds__(256) void rope_kernel(const u16* __restrict__ QKV,
        const float* __restrict__ fcos, const float* __restrict__ fsin,
        u16* __restrict__ q_r, u16* __restrict__ k_r, u16* __restrict__ v_r){
  int row = blockIdx.x;              // b*2048+tok
  int tok = row & 2047;
  int t = threadIdx.x;
  int d0 = t*4;
  int h = d0 >> 6, wd = d0 & 63, i0 = wd >> 1;
  const u16* base = QKV + (size_t)row*3072;
  size_t ob = (((size_t)(row>>11)*16 + h)*2048 + (size_t)tok)*64 + wd;
  float c0 = fcos[tok*32+i0],   s0 = fsin[tok*32+i0];
  float c1 = fcos[tok*32+i0+1], s1 = fsin[tok*32+i0+1];
  const u16* qp = base + d0;
  float x0=b2f(qp[0]), x1=b2f(qp[1]), x2=b2f(qp[2]), x3=b2f(qp[3]);
  q_r[ob]   = f2b((x0*c0-x1*s0)*SCALE_Q_LOG2E);
  q_r[ob+1] = f2b((x0*s0+x1*c0)*SCALE_Q_LOG2E);
  q_r[ob+2] = f2b((x2*c1-x3*s1)*SCALE_Q_LOG2E);
  q_r[ob+3] = f2b((x2*s1+x3*c1)*SCALE_Q_LOG2E);
  const u16* kp = base + 1024 + d0;
  x0=b2f(kp[0]); x1=b2f(kp[1]); x2=b2f(kp[2]); x3=b2f(kp[3]);
  k_r[ob]   = f2b(x0*c0-x1*s0);
  k_r[ob+1] = f2b(x0*s0+x1*c0);
  k_r[ob+2] = f2b(x2*c1-x3*s1);
  k_r[ob+3] = f2b(x2*s1+x3*c1);
  const u16* vp = base + 2048 + d0;
  v_r[ob]=vp[0]; v_r[ob+1]=vp[1]; v_r[ob+2]=vp[2]; v_r[ob+3]=vp[3];
}

// ---------------- flash tile compute on pre-loaded K/V fragments ----------------
static __device__ __forceinline__ void flash_tile(
    const bf16x8 (&kf)[4][2], const s16x4 (&vf)[4][4],
    bf16x8 qf0, bf16x8 qf1, int k0, int q, bool diag,
    int lg, float& mi, float& li, f32x4* oaccT){
  f32x4 sv[4];
  #pragma unroll
  for (int ni=0;ni<4;ni++){
    f32x4 z = {};
    z = __builtin_amdgcn_mfma_f32_16x16x32_bf16(kf[ni][0], qf0, z, 0,0,0);
    z = __builtin_amdgcn_mfma_f32_16x16x32_bf16(kf[ni][1], qf1, z, 0,0,0);
    sv[ni] = z;
  }
  float rm = -1e30f;
  if (diag){
    #pragma unroll
    for (int ni=0;ni<4;ni++)
      #pragma unroll
      for (int r=0;r<4;r++){
        float xs = sv[ni][r];
        if (k0+ni*16+lg*4+r > q) xs = -1e30f;
        sv[ni][r] = xs;
        rm = fmaxf(rm, xs);
      }
  } else {
    #pragma unroll
    for (int ni=0;ni<4;ni++)
      #pragma unroll
      for (int r=0;r<4;r++) rm = fmaxf(rm, sv[ni][r]);
  }
  rm = fmaxf(rm, __shfl_xor(rm, 16, 64));
  rm = fmaxf(rm, __shfl_xor(rm, 32, 64));
  float mn = fmaxf(mi, rm);
  float alpha = exp2f(mi - mn);
  float ls = 0.f;
  s16x4 pf[4];
  #pragma unroll
  for (int ni=0;ni<4;ni++){
    float p0 = exp2f(sv[ni][0]-mn);
    float p1 = exp2f(sv[ni][1]-mn);
    float p2 = exp2f(sv[ni][2]-mn);
    float p3 = exp2f(sv[ni][3]-mn);
    ls += (p0+p1)+(p2+p3);
    s16x4 pp;
    pp[0]=(short)f2b(p0); pp[1]=(short)f2b(p1); pp[2]=(short)f2b(p2); pp[3]=(short)f2b(p3);
    pf[ni]=pp;
  }
  ls += __shfl_xor(ls, 16, 64);
  ls += __shfl_xor(ls, 32, 64);
  li = li*alpha + ls;
  mi = mn;
  #pragma unroll
  for (int dt=0; dt<4; dt++){
    f32x4 oo = oaccT[dt];
    oo[0]*=alpha; oo[1]*=alpha; oo[2]*=alpha; oo[3]*=alpha;
    #pragma unroll
    for (int ni=0;ni<4;ni++)
      oo = mfma16bf(vf[dt][ni], pf[ni], oo);
    oaccT[dt] = oo;
  }
}

// ---------------- flash attention, causal, HD=64; paired q-tiles share staged KV + fragments ----------------
__global__ __launch_bounds__(256,2) void flash_kernel(const u16* __restrict__ q_r,
        const u16* __restrict__ k_r, const u16* __restrict__ v_t, u16* __restrict__ o){
  const int S = 2048;
  int pr = blockIdx.x, bh = blockIdx.y;
  int b = bh>>4, h = bh&15;
  int t = threadIdx.x, w = t>>6, l = t&63, lg = l>>4, ln = l&15;
  __shared__ u16 Ks[2][64*72];   // [token][dim]
  __shared__ u16 Vs[2][64*72];   // [dim][token]
  const u16* qb = q_r + (size_t)bh*S*64;
  const u16* kb = k_r + (size_t)bh*S*64;
  const u16* vb = v_t + (size_t)bh*64*S;
  int rr = t>>2, p16 = (t&3)*16;
  int qlo = pr, qhi = 31-pr;
  int qAr = qlo*64 + w*16 + ln;
  int qBr = qhi*64 + w*16 + ln;
  bf16x8 qA0 = *(const bf16x8*)(qb + (size_t)qAr*64 + lg*8);
  bf16x8 qA1 = *(const bf16x8*)(qb + (size_t)qAr*64 + 32 + lg*8);
  bf16x8 qB0 = *(const bf16x8*)(qb + (size_t)qBr*64 + lg*8);
  bf16x8 qB1 = *(const bf16x8*)(qb + (size_t)qBr*64 + 32 + lg*8);
  f32x4 oA[4] = {}, oB[4] = {};
  float miA=-1e30f, liA=0.f, miB=-1e30f, liB=0.f;
  {
    *(bf16x8*)&Ks[0][rr*72+p16]   = *(const bf16x8*)(kb + (size_t)rr*64 + p16);
    *(bf16x8*)&Ks[0][rr*72+p16+8] = *(const bf16x8*)(kb + (size_t)rr*64 + p16 + 8);
    *(bf16x8*)&Vs[0][rr*72+p16]   = *(const bf16x8*)(vb + (size_t)rr*S + p16);
    *(bf16x8*)&Vs[0][rr*72+p16+8] = *(const bf16x8*)(vb + (size_t)rr*S + p16 + 8);
  }
  __syncthreads();
  for (int kv=0; kv<=qhi; kv++){
    int cur = kv&1;
    int k0 = kv*64;
    bool hasnext = kv < qhi;
    bf16x8 nk0, nk1, nv0, nv1;
    if (hasnext){
      int kn = k0 + 64;
      nk0 = *(const bf16x8*)(kb + (size_t)(kn+rr)*64 + p16);
      nk1 = *(const bf16x8*)(kb + (size_t)(kn+rr)*64 + p16 + 8);
      nv0 = *(const bf16x8*)(vb + (size_t)rr*S + kn + p16);
      nv1 = *(const bf16x8*)(vb + (size_t)rr*S + kn + p16 + 8);
    }
    // hoisted fragment loads -- shared by both paired q-tiles (halves DS traffic)
    bf16x8 kf[4][2]; s16x4 vf[4][4];
    #pragma unroll
    for (int ni=0;ni<4;ni++){
      kf[ni][0] = *(const bf16x8*)&Ks[cur][(ni*16+ln)*72 + lg*8];
      kf[ni][1] = *(const bf16x8*)&Ks[cur][(ni*16+ln)*72 + 32 + lg*8];
    }
    #pragma unroll
    for (int dt=0;dt<4;dt++)
      #pragma unroll
      for (int ni=0;ni<4;ni++)
        vf[dt][ni] = *(const s16x4*)&Vs[cur][(dt*16+ln)*72 + ni*16 + lg*4];
    if (kv <= qlo)
      flash_tile(kf, vf, qA0, qA1, k0, qAr, kv==qlo, lg, miA, liA, oA);
    flash_tile(kf, vf, qB0, qB1, k0, qBr, kv==qhi, lg, miB, liB, oB);
    if (hasnext){
      int nb = cur^1;
      *(bf16x8*)&Ks[nb][rr*72+p16]   = nk0;
      *(bf16x8*)&Ks[nb][rr*72+p16+8] = nk1;
      *(bf16x8*)&Vs[nb][rr*72+p16]   = nv0;
      *(bf16x8*)&Vs[nb][rr*72+p16+8] = nv1;
    }
    __syncthreads();
  }
  {
    u16* ob = o + ((size_t)(b*S+qAr))*1024 + h*64 + lg*4;
    #pragma unroll
    for (int dt=0; dt<4; dt++){
      u16 a0=f2b(oA[dt][0]/liA), a1=f2b(oA[dt][1]/liA);
      u16 a2=f2b(oA[dt][2]/liA), a3=f2b(oA[dt][3]/liA);
      uint2 pv; pv.x = (unsigned)a0 | ((unsigned)a1<<16); pv.y = (unsigned)a2 | ((unsigned)a3<<16);
      *(uint2*)(ob + dt*16) = pv;
    }
  }
  {
    u16* ob = o + ((size_t)(b*S+qBr))*1024 + h*64 + lg*4;
    #pragma unroll
    for (int dt=0; dt<4; dt++){
      u16 a0=f2b(oB[dt][0]/liB), a1=f2b(oB[dt][1]/liB);
      u16 a2=f2b(oB[dt][2]/liB), a3=f2b(oB[dt][3]/liB);
      uint2 pv; pv.x = (unsigned)a0 | ((unsigned)a1<<16); pv.y = (unsigned)a2 | ((unsigned)a3<<16);
      *(uint2*)(ob + dt*16) = pv;
    }
  }
}

extern "C" void kernel_launch(void* const* d_in, const int* in_sizes, int n_in,
                              void* d_out, int out_size, void* d_ws, size_t ws_size,
                              hipStream_t stream) {
  (void)in_sizes; (void)n_in; (void)out_size; (void)ws_size;
  const float* x     = (const float*)d_in[0];
  const float* fcos  = (const float*)d_in[2];
  const float* fsin  = (const float*)d_in[3];
  const float* wr    = (const float*)d_in[4];
  const float* anorm = (const float*)d_in[5];
  const float* wq    = (const float*)d_in[6];
  const float* wk    = (const float*)d_in[7];
  const float* wv    = (const float*)d_in[8];
  const float* wo    = (const float*)d_in[9];
  const float* fnorm = (const float*)d_in[10];
  const float* w1    = (const float*)d_in[11];
  const float* w2    = (const float*)d_in[12];
  const float* w3    = (const float*)d_in[13];
  float* out = (float*)d_out;

  char* W = (char*)d_ws;
  const size_t MB = 1024*1024;
  u16* WqkvT = (u16*)(W + 0);          // 6 MB
  u16* WoT   = (u16*)(W + 6*MB);       // 2 MB
  u16* W13T  = (u16*)(W + 8*MB);       // 16 MB (silu-interleaved)
  u16* W2T   = (u16*)(W + 24*MB);      // 8 MB
  u16* xn    = (u16*)(W + 32*MB);      // 8 MB  (dead after QKV gemm)
  u16* QKV   = (u16*)(W + 40*MB);      // 24 MB (dead after rope)
  u16* q_r   = (u16*)(W + 64*MB);      // 8 MB
  u16* k_r   = (u16*)(W + 72*MB);      // 8 MB
  u16* v_r   = (u16*)(W + 80*MB);      // 8 MB  (dead after v-transpose)
  u16* v_t   = (u16*)(W + 88*MB);      // 8 MB
  u16* attno = (u16*)(W + 96*MB);      // 8 MB  (dead after o-proj)
  float* hbuf= (float*)(W + 104*MB);   // 16 MB f32 (live till W2)
  u16* hn    = (u16*)(W + 120*MB);     // 8 MB  (dead after FFN13)
  u16* g     = (u16*)(W + 128*MB);     // 32 MB
  float* logits = (float*)(W + 160*MB);            // 32 KB
  int*   sel    = (int*)(W + 160*MB + 64*1024);    // 16 KB
  float* rw     = (float*)(W + 160*MB + 96*1024);  // 16 KB
  int*   inv    = (int*)(W + 160*MB + 128*1024);   // 32 KB (unused now, kept for layout)
  (void)inv;

  // prep (weights + router + out-prefill): 16384 + 2048 + 8192 blocks
  prep_kernel<<<26624, 256, 0, stream>>>(wq, wk, wv, wo, w1, w3, w2, x, wr,
                                         WqkvT, WoT, W13T, W2T, logits, out);
  topk_kernel<<<2, 1024, 0, stream>>>(logits, sel, rw, (int*)(W + 160*MB + 128*1024));
  rmsnorm_kernel<<<4096, 256, 0, stream>>>(x, anorm, sel, xn);
  gemm_bt<128,64,u16><<<dim3(24,32), 256, 0, stream>>>(xn, WqkvT, QKV, nullptr, nullptr, 4096, 3072, 1024);
  rope_kernel<<<4096, 256, 0, stream>>>(QKV, fcos, fsin, q_r, k_r, v_r);
  transpose_bf16<<<dim3(2,64,32), dim3(32,8), 0, stream>>>(v_r, v_t, 2048, 64);
  flash_kernel<<<dim3(16,32), 256, 0, stream>>>(q_r, k_r, v_t, attno);
  gemm_bt<64,64,float><<<dim3(16,32), 256, 0, stream>>>(attno, WoT, hbuf, x, sel, 4096, 1024, 1024);
  rmsnorm_kernel<<<4096, 256, 0, stream>>>(hbuf, fnorm, nullptr, hn);
  gemm13<<<dim3(64,32), 256, 0, stream>>>(hn, W13T, g, 1024);
  gemm_w2<<<dim3(16,32), 256, 0, stream>>>(g, W2T, x, hbuf, sel, rw, out, 4096);
}

// Round 8
// 435.968 us; speedup vs baseline: 1.1277x; 1.1277x over previous
//
#include <hip/hip_runtime.h>
#include <cstdint>
#include <cstddef>

typedef unsigned short u16;
typedef unsigned char u8;
typedef __bf16 bf16x8 __attribute__((ext_vector_type(8)));
typedef short s16x4 __attribute__((ext_vector_type(4)));
typedef float f32x4 __attribute__((ext_vector_type(4)));

// q is pre-scaled by 1/sqrt(64) * log2(e) so flash softmax runs in exp2 domain
#define SCALE_Q_LOG2E 0.18033688011112042f
#define W_SCALE 64.0f
#define INV_W_SCALE 0.015625f

static __device__ __forceinline__ float b2f(u16 u){ return __uint_as_float(((unsigned)u)<<16); }
static __device__ __forceinline__ u16 f2b(float f){
  unsigned u = __float_as_uint(f);
  return (u16)((u + 0x7fffu + ((u>>16)&1u)) >> 16);
}
static __device__ __forceinline__ u8 f2fp8(float f){
  return (u8)(__builtin_amdgcn_cvt_pk_fp8_f32(f, f, 0, false) & 0xff);
}
// async global->LDS, 16 B per lane; LDS dest is wave-uniform base + lane*16
static __device__ __forceinline__ void gload_lds16(const void* g, void* l){
  auto gp = reinterpret_cast<__attribute__((address_space(1))) uint32_t*>(reinterpret_cast<uintptr_t>(g));
  auto lp = reinterpret_cast<__attribute__((address_space(3))) uint32_t*>(reinterpret_cast<uintptr_t>(l));
  __builtin_amdgcn_global_load_lds(gp, lp, 16, 0, 0);
}
// 16x16x16 bf16 MFMA (K=16): B-operand k-mapping matches C-layout rows -> P from registers
static __device__ __forceinline__ f32x4 mfma16bf(s16x4 a, s16x4 b, f32x4 c){
#if __has_builtin(__builtin_amdgcn_mfma_f32_16x16x16bf16_1k)
  return __builtin_amdgcn_mfma_f32_16x16x16bf16_1k(a, b, c, 0, 0, 0);
#else
  f32x4 d = c;
  asm volatile("v_mfma_f32_16x16x16_bf16 %0, %1, %2, %0" : "+v"(d) : "v"(a), "v"(b));
  return d;
#endif
}

// ---------------- combined prep: weight transposes (bf16 + fp8x64) + router logits ----------------
__global__ __launch_bounds__(256) void prep_kernel(
    const float* __restrict__ wq, const float* __restrict__ wk,
    const float* __restrict__ wv, const float* __restrict__ wo,
    const float* __restrict__ w1, const float* __restrict__ w3,
    const float* __restrict__ w2, const float* __restrict__ x,
    const float* __restrict__ wr,
    u16* __restrict__ WqkvT, u16* __restrict__ WoT,
    u8* __restrict__ W13T, u8* __restrict__ W2T,
    float* __restrict__ logits){
  __shared__ float tile[32][33];
  int bx = blockIdx.x;
  int t=threadIdx.x, tx=t&31, ty=t>>5;
  if (bx < 4096){
    // bf16 transposes: wq,wk,wv -> WqkvT ; wo -> WoT  (1024x1024 each)
    int wsel = bx>>10, tid = bx&1023;
    const float* in = (wsel==0)?wq:(wsel==1)?wk:(wsel==2)?wv:wo;
    u16* outp = (wsel<3) ? (WqkvT + (size_t)wsel*1024*1024) : WoT;
    int c0=(tid&31)*32, r0=(tid>>5)*32;
    #pragma unroll
    for (int i=0;i<4;i++) tile[ty+i*8][tx] = in[(size_t)(r0+ty+i*8)*1024 + c0+tx];
    __syncthreads();
    #pragma unroll
    for (int i=0;i<4;i++)
      outp[(size_t)(c0+ty+i*8)*1024 + r0+tx] = f2b(tile[tx][ty+i*8]);
  } else if (bx < 12288){
    // fp8 x64 transposes with silu-interleave: w1/w3 -> W13T (8192 x 1024)
    int wsel=(bx-4096)>>12, tid=(bx-4096)&4095;
    const float* in = wsel ? w3 : w1;
    int c0=(tid&127)*32, r0=(tid>>7)*32;
    #pragma unroll
    for (int i=0;i<4;i++) tile[ty+i*8][tx] = in[(size_t)(r0+ty+i*8)*4096 + c0+tx];
    __syncthreads();
    #pragma unroll
    for (int i=0;i<4;i++){
      int c = c0+ty+i*8;
      int orow = (c>>4)*32 + (wsel?16:0) + (c&15);
      W13T[(size_t)orow*1024 + r0+tx] = f2fp8(tile[tx][ty+i*8]*W_SCALE);
    }
  } else if (bx < 16384){
    // fp8 x64 transpose: w2 (4096x1024) -> W2T (1024 x 4096)
    int tid = bx-12288;
    int c0=(tid&31)*32, r0=(tid>>5)*32;
    #pragma unroll
    for (int i=0;i<4;i++) tile[ty+i*8][tx] = w2[(size_t)(r0+ty+i*8)*1024 + c0+tx];
    __syncthreads();
    #pragma unroll
    for (int i=0;i<4;i++)
      W2T[(size_t)(c0+ty+i*8)*4096 + r0+tx] = f2fp8(tile[tx][ty+i*8]*W_SCALE);
  } else {
    // router: 4 rows per block, one wave per row
    int row = (bx-16384)*4 + (t>>6);
    int l = t & 63;
    const float4* xr = (const float4*)(x + (size_t)row*1024) + l;
    const float4* wp = (const float4*)wr + l;
    float acc = 0.f;
    #pragma unroll
    for (int c=0;c<4;c++){
      float4 xv = xr[c*64];
      float4 wv = wp[c*64];
      acc += xv.x*wv.x + xv.y*wv.y + xv.z*wv.z + xv.w*wv.w;
    }
    #pragma unroll
    for (int m=1;m<64;m<<=1) acc += __shfl_xor(acc, m, 64);
    if (l==0) logits[row] = acc;
  }
}

// ---------------- bf16 raw transpose (for V), batched over z ----------------
__global__ __launch_bounds__(256) void transpose_bf16(const u16* __restrict__ in, u16* __restrict__ out,
                                                      int R, int C){
  __shared__ u16 tile[32][33];
  size_t zoff = (size_t)blockIdx.z * R * C;
  const u16* ip = in + zoff;
  u16* op = out + zoff;
  int tx = threadIdx.x, ty = threadIdx.y;
  int c0 = blockIdx.x*32, r0 = blockIdx.y*32;
  #pragma unroll
  for (int i=0;i<4;i++) tile[ty+i*8][tx] = ip[(size_t)(r0+ty+i*8)*C + c0+tx];
  __syncthreads();
  #pragma unroll
  for (int i=0;i<4;i++) op[(size_t)(c0+ty+i*8)*R + r0+tx] = tile[tx][ty+i*8];
}

// ---------------- exact top-K (radix select) + softmax weights ----------------
static __device__ __forceinline__ unsigned mapkey(float f){
  unsigned u = __float_as_uint(f);
  return (u & 0x80000000u) ? ~u : (u | 0x80000000u);
}
static __device__ unsigned blk_scan_excl(unsigned cnt, unsigned* swav){
  int t = threadIdx.x; int l = t&63, w = t>>6;
  unsigned v = cnt;
  #pragma unroll
  for (int off=1; off<64; off<<=1){
    unsigned n = __shfl_up(v, off, 64);
    if (l >= off) v += n;
  }
  __syncthreads();
  if (l==63) swav[w] = v;
  __syncthreads();
  if (t==0){ unsigned c=0; for (int i=0;i<16;i++){ unsigned tmp=swav[i]; swav[i]=c; c+=tmp; } }
  __syncthreads();
  return swav[w] + v - cnt;
}
__global__ __launch_bounds__(1024) void topk_kernel(const float* __restrict__ logits,
        int* __restrict__ sel, float* __restrict__ rw, int* __restrict__ inv){
  int b = blockIdx.x, t = threadIdx.x;
  int l = t&63, w = t>>6;
  __shared__ float vals[4096];
  __shared__ unsigned hist[256];
  __shared__ unsigned swav[16];
  __shared__ float fwav[16];
  __shared__ unsigned sh_prefix, sh_remaining;
  const float* lgp = logits + b*4096;
  for (int i=t;i<4096;i+=1024) vals[i]=lgp[i];
  if (t==0){ sh_prefix=0u; sh_remaining=2048u; }
  __syncthreads();
  for (int level=0; level<4; level++){
    int shift = 24 - level*8;
    if (t<256) hist[t]=0u;
    __syncthreads();
    unsigned pfx = sh_prefix;
    for (int i=t;i<4096;i+=1024){
      unsigned key = mapkey(vals[i]);
      if (level==0 || (key >> (shift+8)) == pfx)
        atomicAdd(&hist[(key>>shift)&255u], 1u);
    }
    __syncthreads();
    if (t==0){
      unsigned rem = sh_remaining, cum=0u; unsigned bsel=0u;
      for (int bin=255; bin>=0; bin--){
        unsigned hc = hist[bin];
        if (cum + hc >= rem){ bsel=(unsigned)bin; break; }
        cum += hc;
      }
      sh_remaining = rem - cum;
      sh_prefix = (pfx<<8) | bsel;
    }
    __syncthreads();
  }
  unsigned T = sh_prefix;
  unsigned req = sh_remaining;
  int i0 = t*4;
  unsigned gt_[4], eq_[4], fl_[4]; float v_[4];
  #pragma unroll
  for (int j=0;j<4;j++){
    v_[j] = vals[i0+j];
    unsigned key = mapkey(v_[j]);
    gt_[j] = key > T ? 1u:0u;
    eq_[j] = key == T ? 1u:0u;
  }
  unsigned eqbase = blk_scan_excl(eq_[0]+eq_[1]+eq_[2]+eq_[3], swav);
  unsigned er = eqbase;
  #pragma unroll
  for (int j=0;j<4;j++){ fl_[j] = gt_[j] | (eq_[j] & (er < req ? 1u:0u)); er += eq_[j]; }
  unsigned pbase = blk_scan_excl(fl_[0]+fl_[1]+fl_[2]+fl_[3], swav);
  unsigned p = pbase;
  #pragma unroll
  for (int j=0;j<4;j++){
    int i = i0+j;
    if (fl_[j]){ sel[b*2048+(int)p]=i; inv[b*4096+i]=(int)p; p++; }
    else inv[b*4096+i] = -1;
  }
  float mx = fmaxf(fmaxf(v_[0],v_[1]), fmaxf(v_[2],v_[3]));
  #pragma unroll
  for (int m=1;m<64;m<<=1) mx = fmaxf(mx, __shfl_xor(mx,m,64));
  __syncthreads();
  if (l==0) fwav[w]=mx;
  __syncthreads();
  if (t==0){ float g=fwav[0]; for(int i=1;i<16;i++) g=fmaxf(g,fwav[i]); fwav[0]=g; }
  __syncthreads();
  float gm = fwav[0];
  float zz = 0.f;
  #pragma unroll
  for (int j=0;j<4;j++) if (fl_[j]) zz += expf(v_[j]-gm);
  #pragma unroll
  for (int m=1;m<64;m<<=1) zz += __shfl_xor(zz,m,64);
  __syncthreads();
  if (l==0) fwav[w]=zz;
  __syncthreads();
  if (t==0){ float s=0.f; for(int i=0;i<16;i++) s+=fwav[i]; fwav[0]=s; }
  __syncthreads();
  float Z = fwav[0];
  unsigned p2 = pbase;
  #pragma unroll
  for (int j=0;j<4;j++) if (fl_[j]){ rw[b*2048+(int)p2] = expf(v_[j]-gm)/Z; p2++; }
}

// ---------------- (gathered) RMSNorm f32 -> bf16 (OT=u16) or fp8 (OT=u8) ----------------
template<typename OT>
__global__ __launch_bounds__(256) void rmsnorm_kernel(const float* __restrict__ xin,
        const float* __restrict__ gamma, const int* __restrict__ sel,
        OT* __restrict__ xn){
  int r = blockIdx.x;
  int src = r;
  if (sel) src = (r>>11)*4096 + sel[r];
  const float* row = xin + (size_t)src*1024;
  int t = threadIdx.x, l = t&63, w = t>>6;
  int d0 = t*4;
  float4 xv = *(const float4*)(row + d0);
  float ss = xv.x*xv.x + xv.y*xv.y + xv.z*xv.z + xv.w*xv.w;
  #pragma unroll
  for (int m=1;m<64;m<<=1) ss += __shfl_xor(ss,m,64);
  __shared__ float red[4];
  if (l==0) red[w]=ss;
  __syncthreads();
  float tot = red[0]+red[1]+red[2]+red[3];
  float rms = rsqrtf(tot*(1.f/1024.f) + 1e-5f);
  float4 gv = *(const float4*)(gamma + d0);
  float v0=xv.x*rms*gv.x, v1=xv.y*rms*gv.y, v2=xv.z*rms*gv.z, v3=xv.w*rms*gv.w;
  if constexpr (sizeof(OT)==2){
    uint2 ov; ov.x = (unsigned)f2b(v0) | ((unsigned)f2b(v1)<<16);
    ov.y = (unsigned)f2b(v2) | ((unsigned)f2b(v3)<<16);
    *(uint2*)(xn + (size_t)r*1024 + d0) = ov;
  } else {
    unsigned pw = (unsigned)__builtin_amdgcn_cvt_pk_fp8_f32(v0, v1, 0, false);
    pw = (unsigned)__builtin_amdgcn_cvt_pk_fp8_f32(v2, v3, (int)pw, true);
    *(unsigned*)((u8*)xn + (size_t)r*1024 + d0) = pw;
  }
}

// XOR-swizzle of 16B blocks within an LDS row: conflict-free power-of-2 strides
template<int NB>  // NB = 16B-blocks per row
static __device__ __forceinline__ int swz(int row, int blk){
  if constexpr (NB==8) return blk ^ (row&7);
  else if constexpr (NB==4) return blk ^ ((row>>1)&3);
  else return blk ^ ((row>>1)&3);
}

// ---------------- generic bf16 GEMM: C = A(128xK) * Bt(BNxK)^T (+resid/gather) ----------------
template<int BN, int BK, typename OT>
__global__ __launch_bounds__(256,2) void gemm_bt(const u16* __restrict__ A, const u16* __restrict__ Bt,
        OT* __restrict__ C, const float* __restrict__ resid, const int* __restrict__ sel,
        int M, int N, int Kd){
  __shared__ u16 As[128*BK];
  __shared__ u16 Bs[BN*BK];
  constexpr int NF = BN/32;
  constexpr int KK = BK/32;
  constexpr int NB = BK/8;       // 16B blocks per row
  int t = threadIdx.x, w = t>>6, l = t&63, lg = l>>4, ln = l&15;
  int m0 = blockIdx.y*128, n0 = blockIdx.x*BN;
  int wm = (w&1)*64, wn = (w>>1)*(BN/2);
  f32x4 acc[4][NF] = {};
  for (int k0=0; k0<Kd; k0+=BK){
    __syncthreads();
    #pragma unroll
    for (int c=0;c<128*BK*2/4096;c++){
      int off = t*16 + c*4096;
      int row = off/(BK*2), pb = (off%(BK*2))>>4;
      gload_lds16(A + (size_t)(m0+row)*Kd + k0 + swz<NB>(row,pb)*8, &As[c*2048 + w*512]);
    }
    #pragma unroll
    for (int c=0;c<BN*BK*2/4096;c++){
      int off = t*16 + c*4096;
      int row = off/(BK*2), pb = (off%(BK*2))>>4;
      gload_lds16(Bt + (size_t)(n0+row)*Kd + k0 + swz<NB>(row,pb)*8, &Bs[c*2048 + w*512]);
    }
    __syncthreads();
    #pragma unroll
    for (int kk=0;kk<KK;kk++){
      bf16x8 af[4], bfv[NF];
      #pragma unroll
      for (int i=0;i<4;i++){
        int r = wm+i*16+ln;
        af[i] = *(const bf16x8*)&As[r*BK + swz<NB>(r, kk*4+lg)*8];
      }
      #pragma unroll
      for (int i=0;i<NF;i++){
        int r = wn+i*16+ln;
        bfv[i] = *(const bf16x8*)&Bs[r*BK + swz<NB>(r, kk*4+lg)*8];
      }
      #pragma unroll
      for (int mi=0;mi<4;mi++)
        #pragma unroll
        for (int ni=0;ni<NF;ni++)
          acc[mi][ni] = __builtin_amdgcn_mfma_f32_16x16x32_bf16(af[mi], bfv[ni], acc[mi][ni], 0,0,0);
    }
  }
  #pragma unroll
  for (int mi=0;mi<4;mi++){
    #pragma unroll
    for (int ni=0;ni<NF;ni++){
      #pragma unroll
      for (int r=0;r<4;r++){
        int row = m0+wm+mi*16+lg*4+r;
        int col = n0+wn+ni*16+ln;
        float v = acc[mi][ni][r];
        if (resid){
          size_t rrow = sel ? ((size_t)(row>>11)*4096 + sel[row]) : (size_t)row;
          v += resid[rrow*N + col];
        }
        if constexpr (sizeof(OT)==2) C[(size_t)row*N + col] = f2b(v);
        else                          C[(size_t)row*N + col] = v;
      }
    }
  }
}

// ---------------- FFN13 fp8 GEMM with fused SwiGLU epilogue (BK=128 fp8, swizzled) ----------------
// A = hn8 (4096x1024 fp8), Bt = W13T (8192x1024 fp8, x64-scaled, silu-interleaved).
// g output fp8 (4096x4096).
__global__ __launch_bounds__(256,2) void gemm13(const u8* __restrict__ A, const u8* __restrict__ Bt,
        u8* __restrict__ g, int Kd){
  constexpr int BK = 128;        // fp8 elems per row = 128 B, 8x 16B blocks
  __shared__ u8 As[128*BK];      // 16 KB
  __shared__ u8 Bs[128*BK];      // 16 KB
  int t = threadIdx.x, w = t>>6, l = t&63, lg = l>>4, ln = l&15;
  int m0 = blockIdx.y*128, n0 = blockIdx.x*128;
  int wm = (w&1)*64, wn = (w>>1)*64;
  f32x4 acc[4][4] = {};
  for (int k0=0; k0<Kd; k0+=BK){
    __syncthreads();
    #pragma unroll
    for (int c=0;c<4;c++){
      int off = t*16 + c*4096;
      int row = off>>7, pb = (off&127)>>4;
      gload_lds16(A  + (size_t)(m0+row)*Kd + k0 + ((pb^(row&7))<<4), &As[c*4096 + w*1024]);
      gload_lds16(Bt + (size_t)(n0+row)*Kd + k0 + ((pb^(row&7))<<4), &Bs[c*4096 + w*1024]);
    }
    __syncthreads();
    #pragma unroll
    for (int kk=0;kk<4;kk++){
      long long af[4], bfv[4];
      #pragma unroll
      for (int i=0;i<4;i++){
        int ra = wm+i*16+ln, rb = wn+i*16+ln;
        int g0 = kk*2 + (lg>>1), ho = (lg&1)*8;
        af[i]  = *(const long long*)&As[ra*BK + ((g0^(ra&7))<<4) + ho];
        bfv[i] = *(const long long*)&Bs[rb*BK + ((g0^(rb&7))<<4) + ho];
      }
      #pragma unroll
      for (int mi=0;mi<4;mi++)
        #pragma unroll
        for (int ni=0;ni<4;ni++)
          acc[mi][ni] = __builtin_amdgcn_mfma_f32_16x16x32_fp8_fp8(af[mi], bfv[ni], acc[mi][ni], 0,0,0);
    }
  }
  int gbase = (n0+wn)>>1;
  #pragma unroll
  for (int mi=0;mi<4;mi++){
    #pragma unroll
    for (int p=0;p<2;p++){
      #pragma unroll
      for (int r=0;r<4;r++){
        int row = m0+wm+mi*16+lg*4+r;
        int col = gbase + p*16 + ln;
        float a1 = acc[mi][2*p][r]*INV_W_SCALE, a3 = acc[mi][2*p+1][r]*INV_W_SCALE;
        float s1 = a1 / (1.f + __expf(-a1));
        g[(size_t)row*4096 + col] = f2fp8(s1*a3);
      }
    }
  }
}

// ---------------- W2 fp8 GEMM with fused MoD scatter epilogue ----------------
// A = g (4096x4096 fp8), Bt = W2T (1024x4096 fp8 x64). out[b,sel[row]] = x + rw*(hbuf + y/64)
__global__ __launch_bounds__(256,2) void gemm_w2(const u8* __restrict__ A, const u8* __restrict__ Bt,
        const float* __restrict__ x, const float* __restrict__ hbuf,
        const int* __restrict__ sel, const float* __restrict__ rw,
        float* __restrict__ out, int Kd){
  constexpr int BN = 64, BK = 128;
  __shared__ u8 As[128*BK];      // 16 KB
  __shared__ u8 Bs[BN*BK];       // 8 KB
  int t = threadIdx.x, w = t>>6, l = t&63, lg = l>>4, ln = l&15;
  int m0 = blockIdx.y*128, n0 = blockIdx.x*BN;
  int wm = (w&1)*64, wn = (w>>1)*(BN/2);
  f32x4 acc[4][2] = {};
  for (int k0=0; k0<Kd; k0+=BK){
    __syncthreads();
    #pragma unroll
    for (int c=0;c<4;c++){
      int off = t*16 + c*4096;
      int row = off>>7, pb = (off&127)>>4;
      gload_lds16(A + (size_t)(m0+row)*Kd + k0 + ((pb^(row&7))<<4), &As[c*4096 + w*1024]);
    }
    #pragma unroll
    for (int c=0;c<2;c++){
      int off = t*16 + c*4096;
      int row = off>>7, pb = (off&127)>>4;
      gload_lds16(Bt + (size_t)(n0+row)*Kd + k0 + ((pb^(row&7))<<4), &Bs[c*4096 + w*1024]);
    }
    __syncthreads();
    #pragma unroll
    for (int kk=0;kk<4;kk++){
      long long af[4], bfv[2];
      int g0 = kk*2 + (lg>>1), ho = (lg&1)*8;
      #pragma unroll
      for (int i=0;i<4;i++){
        int r = wm+i*16+ln;
        af[i] = *(const long long*)&As[r*BK + ((g0^(r&7))<<4) + ho];
      }
      #pragma unroll
      for (int i=0;i<2;i++){
        int r = wn+i*16+ln;
        bfv[i] = *(const long long*)&Bs[r*BK + ((g0^(r&7))<<4) + ho];
      }
      #pragma unroll
      for (int mi=0;mi<4;mi++)
        #pragma unroll
        for (int ni=0;ni<2;ni++)
          acc[mi][ni] = __builtin_amdgcn_mfma_f32_16x16x32_fp8_fp8(af[mi], bfv[ni], acc[mi][ni], 0,0,0);
    }
  }
  #pragma unroll
  for (int mi=0;mi<4;mi++){
    int row0 = m0+wm+mi*16+lg*4;
    #pragma unroll
    for (int r=0;r<4;r++){
      int row = row0+r;
      int b = row>>11;
      size_t srow = (size_t)b*4096 + sel[row];
      float wgt = rw[row];
      #pragma unroll
      for (int ni=0;ni<2;ni++){
        int col = n0+wn+ni*16+ln;
        float y = acc[mi][ni][r]*INV_W_SCALE;
        out[srow*1024 + col] = x[srow*1024 + col] + wgt*(hbuf[(size_t)row*1024 + col] + y);
      }
    }
  }
}

// ---------------- RoPE + QKV unpack (q scaled by 1/sqrt(HD)*log2e) ----------------
__global__ __launch_bounds__(256) void rope_kernel(const u16* __restrict__ QKV,
        const float* __restrict__ fcos, const float* __restrict__ fsin,
        u16* __restrict__ q_r, u16* __restrict__ k_r, u16* __restrict__ v_r){
  int row = blockIdx.x;              // b*2048+tok
  int tok = row & 2047;
  int t = threadIdx.x;
  int d0 = t*4;
  int h = d0 >> 6, wd = d0 & 63, i0 = wd >> 1;
  const u16* base = QKV + (size_t)row*3072;
  size_t ob = (((size_t)(row>>11)*16 + h)*2048 + (size_t)tok)*64 + wd;
  float c0 = fcos[tok*32+i0],   s0 = fsin[tok*32+i0];
  float c1 = fcos[tok*32+i0+1], s1 = fsin[tok*32+i0+1];
  const u16* qp = base + d0;
  float x0=b2f(qp[0]), x1=b2f(qp[1]), x2=b2f(qp[2]), x3=b2f(qp[3]);
  q_r[ob]   = f2b((x0*c0-x1*s0)*SCALE_Q_LOG2E);
  q_r[ob+1] = f2b((x0*s0+x1*c0)*SCALE_Q_LOG2E);
  q_r[ob+2] = f2b((x2*c1-x3*s1)*SCALE_Q_LOG2E);
  q_r[ob+3] = f2b((x2*s1+x3*c1)*SCALE_Q_LOG2E);
  const u16* kp = base + 1024 + d0;
  x0=b2f(kp[0]); x1=b2f(kp[1]); x2=b2f(kp[2]); x3=b2f(kp[3]);
  k_r[ob]   = f2b(x0*c0-x1*s0);
  k_r[ob+1] = f2b(x0*s0+x1*c0);
  k_r[ob+2] = f2b(x2*c1-x3*s1);
  k_r[ob+3] = f2b(x2*s1+x3*c1);
  const u16* vp = base + 2048 + d0;
  v_r[ob]=vp[0]; v_r[ob+1]=vp[1]; v_r[ob+2]=vp[2]; v_r[ob+3]=vp[3];
}

// ---------------- flash tile compute on pre-loaded K/V fragments ----------------
static __device__ __forceinline__ void flash_tile(
    const bf16x8 (&kf)[4][2], const s16x4 (&vf)[4][4],
    bf16x8 qf0, bf16x8 qf1, int k0, int q, bool diag,
    int lg, float& mi, float& li, f32x4* oaccT){
  f32x4 sv[4];
  #pragma unroll
  for (int ni=0;ni<4;ni++){
    f32x4 z = {};
    z = __builtin_amdgcn_mfma_f32_16x16x32_bf16(kf[ni][0], qf0, z, 0,0,0);
    z = __builtin_amdgcn_mfma_f32_16x16x32_bf16(kf[ni][1], qf1, z, 0,0,0);
    sv[ni] = z;
  }
  float rm = -1e30f;
  if (diag){
    #pragma unroll
    for (int ni=0;ni<4;ni++)
      #pragma unroll
      for (int r=0;r<4;r++){
        float xs = sv[ni][r];
        if (k0+ni*16+lg*4+r > q) xs = -1e30f;
        sv[ni][r] = xs;
        rm = fmaxf(rm, xs);
      }
  } else {
    #pragma unroll
    for (int ni=0;ni<4;ni++)
      #pragma unroll
      for (int r=0;r<4;r++) rm = fmaxf(rm, sv[ni][r]);
  }
  rm = fmaxf(rm, __shfl_xor(rm, 16, 64));
  rm = fmaxf(rm, __shfl_xor(rm, 32, 64));
  float mn = fmaxf(mi, rm);
  float alpha = exp2f(mi - mn);
  float ls = 0.f;
  s16x4 pf[4];
  #pragma unroll
  for (int ni=0;ni<4;ni++){
    float p0 = exp2f(sv[ni][0]-mn);
    float p1 = exp2f(sv[ni][1]-mn);
    float p2 = exp2f(sv[ni][2]-mn);
    float p3 = exp2f(sv[ni][3]-mn);
    ls += (p0+p1)+(p2+p3);
    s16x4 pp;
    pp[0]=(short)f2b(p0); pp[1]=(short)f2b(p1); pp[2]=(short)f2b(p2); pp[3]=(short)f2b(p3);
    pf[ni]=pp;
  }
  ls += __shfl_xor(ls, 16, 64);
  ls += __shfl_xor(ls, 32, 64);
  li = li*alpha + ls;
  mi = mn;
  #pragma unroll
  for (int dt=0; dt<4; dt++){
    f32x4 oo = oaccT[dt];
    oo[0]*=alpha; oo[1]*=alpha; oo[2]*=alpha; oo[3]*=alpha;
    #pragma unroll
    for (int ni=0;ni<4;ni++)
      oo = mfma16bf(vf[dt][ni], pf[ni], oo);
    oaccT[dt] = oo;
  }
}

// ---------------- flash attention, causal, HD=64; paired q-tiles share staged KV + fragments ----------------
__global__ __launch_bounds__(256,2) void flash_kernel(const u16* __restrict__ q_r,
        const u16* __restrict__ k_r, const u16* __restrict__ v_t, u16* __restrict__ o){
  const int S = 2048;
  int pr = blockIdx.x, bh = blockIdx.y;
  int b = bh>>4, h = bh&15;
  int t = threadIdx.x, w = t>>6, l = t&63, lg = l>>4, ln = l&15;
  __shared__ u16 Ks[2][64*72];   // [token][dim]
  __shared__ u16 Vs[2][64*72];   // [dim][token]
  const u16* qb = q_r + (size_t)bh*S*64;
  const u16* kb = k_r + (size_t)bh*S*64;
  const u16* vb = v_t + (size_t)bh*64*S;
  int rr = t>>2, p16 = (t&3)*16;
  int qlo = pr, qhi = 31-pr;
  int qAr = qlo*64 + w*16 + ln;
  int qBr = qhi*64 + w*16 + ln;
  bf16x8 qA0 = *(const bf16x8*)(qb + (size_t)qAr*64 + lg*8);
  bf16x8 qA1 = *(const bf16x8*)(qb + (size_t)qAr*64 + 32 + lg*8);
  bf16x8 qB0 = *(const bf16x8*)(qb + (size_t)qBr*64 + lg*8);
  bf16x8 qB1 = *(const bf16x8*)(qb + (size_t)qBr*64 + 32 + lg*8);
  f32x4 oA[4] = {}, oB[4] = {};
  float miA=-1e30f, liA=0.f, miB=-1e30f, liB=0.f;
  {
    *(bf16x8*)&Ks[0][rr*72+p16]   = *(const bf16x8*)(kb + (size_t)rr*64 + p16);
    *(bf16x8*)&Ks[0][rr*72+p16+8] = *(const bf16x8*)(kb + (size_t)rr*64 + p16 + 8);
    *(bf16x8*)&Vs[0][rr*72+p16]   = *(const bf16x8*)(vb + (size_t)rr*S + p16);
    *(bf16x8*)&Vs[0][rr*72+p16+8] = *(const bf16x8*)(vb + (size_t)rr*S + p16 + 8);
  }
  __syncthreads();
  for (int kv=0; kv<=qhi; kv++){
    int cur = kv&1;
    int k0 = kv*64;
    bool hasnext = kv < qhi;
    bf16x8 nk0, nk1, nv0, nv1;
    if (hasnext){
      int kn = k0 + 64;
      nk0 = *(const bf16x8*)(kb + (size_t)(kn+rr)*64 + p16);
      nk1 = *(const bf16x8*)(kb + (size_t)(kn+rr)*64 + p16 + 8);
      nv0 = *(const bf16x8*)(vb + (size_t)rr*S + kn + p16);
      nv1 = *(const bf16x8*)(vb + (size_t)rr*S + kn + p16 + 8);
    }
    bf16x8 kf[4][2]; s16x4 vf[4][4];
    #pragma unroll
    for (int ni=0;ni<4;ni++){
      kf[ni][0] = *(const bf16x8*)&Ks[cur][(ni*16+ln)*72 + lg*8];
      kf[ni][1] = *(const bf16x8*)&Ks[cur][(ni*16+ln)*72 + 32 + lg*8];
    }
    #pragma unroll
    for (int dt=0;dt<4;dt++)
      #pragma unroll
      for (int ni=0;ni<4;ni++)
        vf[dt][ni] = *(const s16x4*)&Vs[cur][(dt*16+ln)*72 + ni*16 + lg*4];
    if (kv <= qlo)
      flash_tile(kf, vf, qA0, qA1, k0, qAr, kv==qlo, lg, miA, liA, oA);
    flash_tile(kf, vf, qB0, qB1, k0, qBr, kv==qhi, lg, miB, liB, oB);
    if (hasnext){
      int nb = cur^1;
      *(bf16x8*)&Ks[nb][rr*72+p16]   = nk0;
      *(bf16x8*)&Ks[nb][rr*72+p16+8] = nk1;
      *(bf16x8*)&Vs[nb][rr*72+p16]   = nv0;
      *(bf16x8*)&Vs[nb][rr*72+p16+8] = nv1;
    }
    __syncthreads();
  }
  {
    u16* ob = o + ((size_t)(b*S+qAr))*1024 + h*64 + lg*4;
    #pragma unroll
    for (int dt=0; dt<4; dt++){
      u16 a0=f2b(oA[dt][0]/liA), a1=f2b(oA[dt][1]/liA);
      u16 a2=f2b(oA[dt][2]/liA), a3=f2b(oA[dt][3]/liA);
      uint2 pv; pv.x = (unsigned)a0 | ((unsigned)a1<<16); pv.y = (unsigned)a2 | ((unsigned)a3<<16);
      *(uint2*)(ob + dt*16) = pv;
    }
  }
  {
    u16* ob = o + ((size_t)(b*S+qBr))*1024 + h*64 + lg*4;
    #pragma unroll
    for (int dt=0; dt<4; dt++){
      u16 a0=f2b(oB[dt][0]/liB), a1=f2b(oB[dt][1]/liB);
      u16 a2=f2b(oB[dt][2]/liB), a3=f2b(oB[dt][3]/liB);
      uint2 pv; pv.x = (unsigned)a0 | ((unsigned)a1<<16); pv.y = (unsigned)a2 | ((unsigned)a3<<16);
      *(uint2*)(ob + dt*16) = pv;
    }
  }
}

extern "C" void kernel_launch(void* const* d_in, const int* in_sizes, int n_in,
                              void* d_out, int out_size, void* d_ws, size_t ws_size,
                              hipStream_t stream) {
  (void)in_sizes; (void)n_in; (void)out_size; (void)ws_size;
  const float* x     = (const float*)d_in[0];
  const float* fcos  = (const float*)d_in[2];
  const float* fsin  = (const float*)d_in[3];
  const float* wr    = (const float*)d_in[4];
  const float* anorm = (const float*)d_in[5];
  const float* wq    = (const float*)d_in[6];
  const float* wk    = (const float*)d_in[7];
  const float* wv    = (const float*)d_in[8];
  const float* wo    = (const float*)d_in[9];
  const float* fnorm = (const float*)d_in[10];
  const float* w1    = (const float*)d_in[11];
  const float* w2    = (const float*)d_in[12];
  const float* w3    = (const float*)d_in[13];
  float* out = (float*)d_out;

  char* W = (char*)d_ws;
  const size_t MB = 1024*1024;
  u16* WqkvT = (u16*)(W + 0);          // 6 MB bf16
  u16* WoT   = (u16*)(W + 6*MB);       // 2 MB bf16
  u8*  W13T  = (u8*)(W + 8*MB);        // 8 MB fp8 (x64-scaled, silu-interleaved)
  u8*  W2T   = (u8*)(W + 16*MB);       // 4 MB fp8 (x64)
  u16* xn    = (u16*)(W + 20*MB);      // 8 MB bf16 (dead after QKV gemm)
  u16* QKV   = (u16*)(W + 28*MB);      // 24 MB (dead after rope)
  u16* q_r   = (u16*)(W + 52*MB);      // 8 MB
  u16* k_r   = (u16*)(W + 60*MB);      // 8 MB
  u16* v_r   = (u16*)(W + 68*MB);      // 8 MB (dead after v-transpose)
  u16* v_t   = (u16*)(W + 76*MB);      // 8 MB
  u16* attno = (u16*)(W + 84*MB);      // 8 MB (dead after o-proj)
  float* hbuf= (float*)(W + 92*MB);    // 16 MB f32 (live till W2)
  u8*  hn8   = (u8*)(W + 108*MB);      // 4 MB fp8 (dead after FFN13)
  u8*  g     = (u8*)(W + 112*MB);      // 16 MB fp8
  float* logits = (float*)(W + 128*MB);            // 32 KB
  int*   sel    = (int*)(W + 128*MB + 64*1024);    // 16 KB
  float* rw     = (float*)(W + 128*MB + 96*1024);  // 16 KB
  int*   inv    = (int*)(W + 128*MB + 128*1024);   // 32 KB

  // out = x prefill via DMA (selected rows later overwritten by gemm_w2 scatter)
  hipMemcpyAsync(out, x, (size_t)8192*1024*4, hipMemcpyDeviceToDevice, stream);
  // prep: 16384 transpose blocks + 2048 router blocks
  prep_kernel<<<18432, 256, 0, stream>>>(wq, wk, wv, wo, w1, w3, w2, x, wr,
                                         WqkvT, WoT, W13T, W2T, logits);
  topk_kernel<<<2, 1024, 0, stream>>>(logits, sel, rw, inv);
  rmsnorm_kernel<u16><<<4096, 256, 0, stream>>>(x, anorm, sel, xn);
  gemm_bt<128,64,u16><<<dim3(24,32), 256, 0, stream>>>(xn, WqkvT, QKV, nullptr, nullptr, 4096, 3072, 1024);
  rope_kernel<<<4096, 256, 0, stream>>>(QKV, fcos, fsin, q_r, k_r, v_r);
  transpose_bf16<<<dim3(2,64,32), dim3(32,8), 0, stream>>>(v_r, v_t, 2048, 64);
  flash_kernel<<<dim3(16,32), 256, 0, stream>>>(q_r, k_r, v_t, attno);
  gemm_bt<64,64,float><<<dim3(16,32), 256, 0, stream>>>(attno, WoT, hbuf, x, sel, 4096, 1024, 1024);
  rmsnorm_kernel<u8><<<4096, 256, 0, stream>>>(hbuf, fnorm, nullptr, hn8);
  gemm13<<<dim3(64,32), 256, 0, stream>>>(hn8, W13T, g, 1024);
  gemm_w2<<<dim3(16,32), 256, 0, stream>>>(g, W2T, x, hbuf, sel, rw, out, 4096);
}